// Round 8
// baseline (611.825 us; speedup 1.0000x reference)
//
#include <hip/hip_runtime.h>
#include <hip/hip_bf16.h>

#define N_NODES 10000
#define E_EDGES 160000

typedef __attribute__((ext_vector_type(8))) short bf16x8;
typedef __attribute__((ext_vector_type(4))) float f32x4;

__device__ __forceinline__ unsigned short f2b(float f) {
    unsigned int u = __float_as_uint(f);
    u = (u + 0x7fffu + ((u >> 16) & 1u)) >> 16;
    return (unsigned short)u;
}

__device__ __forceinline__ float b2f(unsigned short u) {
    return __uint_as_float(((unsigned int)u) << 16);
}

__device__ __forceinline__ float tanh_fast(float x) {
    float ax = fabsf(x);
    float e = __expf(-2.f * ax);
    float r = (1.f - e) / (1.f + e);
    return copysignf(r, x);
}

// ---------------- small GCN-prep kernels ----------------
__global__ void init_kernel(float* deg, int* cnt) {
    int i = blockIdx.x * 256 + threadIdx.x;
    if (i < N_NODES) { deg[i] = 1.0f; cnt[i] = 0; }   // 1.0 = self-loop weight
}

__global__ void deg_add_kernel(const int* __restrict__ ei, const float* __restrict__ ew,
                               float* deg, int* cnt) {
    int e = blockIdx.x * 256 + threadIdx.x;
    if (e < E_EDGES) {
        int c = ei[E_EDGES + e];
        atomicAdd(&deg[c], ew[e]);
        atomicAdd(&cnt[c], 1);
    }
}

__global__ void dinv_kernel(const float* __restrict__ deg, float* dinv) {
    int i = blockIdx.x * 256 + threadIdx.x;
    if (i < N_NODES) { float d = deg[i]; dinv[i] = d > 0.f ? rsqrtf(d) : 0.f; }
}

// exclusive prefix sum of cnt[N] -> offs[N+1], cursor[N]
__global__ void scan_kernel(const int* __restrict__ cnt, int* offs, int* cursor) {
    __shared__ int tsum[1024];
    int t = threadIdx.x;
    int base = t * 10;
    int loc[10];
    int s = 0;
    #pragma unroll
    for (int j = 0; j < 10; ++j) {
        int i = base + j;
        int v = (i < N_NODES) ? cnt[i] : 0;
        loc[j] = s; s += v;
    }
    tsum[t] = s;
    __syncthreads();
    for (int d = 1; d < 1024; d <<= 1) {
        int v = (t >= d) ? tsum[t - d] : 0;
        __syncthreads();
        tsum[t] += v;
        __syncthreads();
    }
    int pre = tsum[t] - s;   // exclusive
    #pragma unroll
    for (int j = 0; j < 10; ++j) {
        int i = base + j;
        if (i < N_NODES) { offs[i] = pre + loc[j]; cursor[i] = pre + loc[j]; }
    }
    if (t == 1023) offs[N_NODES] = tsum[1023];
}

__global__ void fill_kernel(const int* __restrict__ ei, const float* __restrict__ ew,
                            const float* __restrict__ dinv, int* cursor,
                            int* erow, float* enorm) {
    int e = blockIdx.x * 256 + threadIdx.x;
    if (e < E_EDGES) {
        int r = ei[e], c = ei[E_EDGES + e];
        float nm = dinv[r] * ew[e] * dinv[c];
        int pos = atomicAdd(&cursor[c], 1);
        erow[pos] = r; enorm[pos] = nm;
    }
}

// ---- weight -> bf16 MFMA-fragment-major layout: frag(nf,ks) = 1KB, lane-major ----
template<int KS, int K>
__global__ void wconv_kernel(const float* __restrict__ w, unsigned short* __restrict__ o) {
    int idx = blockIdx.x * 256 + threadIdx.x;   // frag*64 + lane
    int lane = idx & 63, frag = idx >> 6;
    int nf = frag / KS, ks = frag % KS;
    const float* src = w + (nf * 16 + (lane & 15)) * K + ks * 32 + (lane >> 4) * 8;
    unsigned short* dst = o + frag * 512 + lane * 8;
    float4 v0 = *(const float4*)src;
    float4 v1 = *(const float4*)(src + 4);
    ushort4 h0; h0.x = f2b(v0.x); h0.y = f2b(v0.y); h0.z = f2b(v0.z); h0.w = f2b(v0.w);
    ushort4 h1; h1.x = f2b(v1.x); h1.y = f2b(v1.y); h1.z = f2b(v1.z); h1.w = f2b(v1.w);
    *(ushort4*)dst = h0;
    *(ushort4*)(dst + 4) = h1;
}

// -------------- CSR gather-aggregate: 2 waves per target node (8 graphs each) ----------------
// xlt layout: [N][G=16][64] bf16. gc layout: [G][N][64] bf16 (== seq flat rows)
__global__ __launch_bounds__(256) void aggregate_kernel(
        const unsigned short* __restrict__ xlt, const int* __restrict__ erow,
        const float* __restrict__ enorm, const int* __restrict__ offs,
        const float* __restrict__ dinv, const float* __restrict__ gcn_b,
        unsigned short* __restrict__ gc) {
    int gwid = (blockIdx.x * 256 + threadIdx.x) >> 6;   // 20000 waves
    int c = gwid >> 1;
    int gh = (gwid & 1) * 8;
    int lane = threadIdx.x & 63;
    if (c >= N_NODES) return;
    float acc[8];
    float d = dinv[c];
    float wself = d * d;
    const unsigned short* xr = xlt + (long)c * 1024 + gh * 64;
    #pragma unroll
    for (int g = 0; g < 8; ++g) acc[g] = b2f(xr[g * 64 + lane]) * wself;
    int e0 = offs[c], e1 = offs[c + 1];
    for (int e = e0; e < e1; ++e) {
        int r = erow[e];
        float nm = enorm[e];
        const unsigned short* xs = xlt + (long)r * 1024 + gh * 64;
        #pragma unroll
        for (int g = 0; g < 8; ++g) acc[g] += b2f(xs[g * 64 + lane]) * nm;
    }
    float bb = gcn_b[lane];
    #pragma unroll
    for (int g = 0; g < 8; ++g)
        gc[(long)(gh + g) * 640000 + (long)c * 64 + lane] = f2b(acc[g] + bb);
}

// -------------- generic bf16-MFMA GEMM: C[m,n] = A[m,:K] . W[n,:K] + bias ----------------
// BM=128, BK=64, 4 waves (2x2). EPI: 0=xlt scatter bf16, 2=bf16(+relu)
template<int NTOT, int BN, int KTOT, bool AF32, int EPI, bool RELU>
__global__ __launch_bounds__(256) void gemm_kernel(
        const void* __restrict__ Aptr, const float* __restrict__ Wp,
        const float* __restrict__ bias0, const float* __restrict__ bias1,
        void* __restrict__ outp) {
    constexpr int WN = BN / 2;
    constexpr int FN = WN / 16;
    __shared__ __align__(16) unsigned short As[128 * 72];
    __shared__ __align__(16) unsigned short Bs[BN * 72];
    const int tid = threadIdx.x;
    const int lane = tid & 63;
    const int wid = tid >> 6;
    const int wm = wid >> 1, wn = wid & 1;
    const long m0 = (long)blockIdx.x * 128;
    const int n0 = blockIdx.y * BN;

    f32x4 acc[4][FN];
    #pragma unroll
    for (int a = 0; a < 4; ++a)
        #pragma unroll
        for (int b = 0; b < FN; ++b)
            acc[a][b] = (f32x4){0.f, 0.f, 0.f, 0.f};

    for (int kt = 0; kt < KTOT / 64; ++kt) {
        if (AF32) {
            const float* Ag = (const float*)Aptr;
            #pragma unroll
            for (int p = 0; p < 8; ++p) {
                int idx = p * 256 + tid;
                int r = idx >> 4, c4 = idx & 15;
                float4 v = *(const float4*)(Ag + (m0 + r) * KTOT + kt * 64 + c4 * 4);
                ushort4 h; h.x = f2b(v.x); h.y = f2b(v.y); h.z = f2b(v.z); h.w = f2b(v.w);
                *(ushort4*)&As[r * 72 + c4 * 4] = h;
            }
        } else {
            const unsigned short* Ag = (const unsigned short*)Aptr;
            #pragma unroll
            for (int p = 0; p < 4; ++p) {
                int idx = p * 256 + tid;
                int r = idx >> 3, c8 = idx & 7;
                *(int4*)&As[r * 72 + c8 * 8] = *(const int4*)(Ag + (m0 + r) * KTOT + kt * 64 + c8 * 8);
            }
        }
        #pragma unroll
        for (int p = 0; p < BN / 16; ++p) {
            int idx = p * 256 + tid;
            int r = idx >> 4, c4 = idx & 15;
            float4 v = *(const float4*)(Wp + (long)(n0 + r) * KTOT + kt * 64 + c4 * 4);
            ushort4 h; h.x = f2b(v.x); h.y = f2b(v.y); h.z = f2b(v.z); h.w = f2b(v.w);
            *(ushort4*)&Bs[r * 72 + c4 * 4] = h;
        }
        __syncthreads();
        #pragma unroll
        for (int ks = 0; ks < 2; ++ks) {
            bf16x8 a[4], b[FN];
            #pragma unroll
            for (int fm = 0; fm < 4; ++fm)
                a[fm] = *(const bf16x8*)&As[(wm * 64 + fm * 16 + (lane & 15)) * 72 + ks * 32 + (lane >> 4) * 8];
            #pragma unroll
            for (int fn = 0; fn < FN; ++fn)
                b[fn] = *(const bf16x8*)&Bs[(wn * WN + fn * 16 + (lane & 15)) * 72 + ks * 32 + (lane >> 4) * 8];
            #pragma unroll
            for (int fm = 0; fm < 4; ++fm)
                #pragma unroll
                for (int fn = 0; fn < FN; ++fn)
                    acc[fm][fn] = __builtin_amdgcn_mfma_f32_16x16x32_bf16(a[fm], b[fn], acc[fm][fn], 0, 0, 0);
        }
        __syncthreads();
    }

    #pragma unroll
    for (int fm = 0; fm < 4; ++fm) {
        #pragma unroll
        for (int fn = 0; fn < FN; ++fn) {
            const int colg = n0 + wn * WN + fn * 16 + (lane & 15);
            float bv = 0.f;
            if (bias0) bv += bias0[colg];
            if (bias1) bv += bias1[colg];
            #pragma unroll
            for (int r = 0; r < 4; ++r) {
                int row = (int)m0 + wm * 64 + fm * 16 + (lane >> 4) * 4 + r;
                float v = acc[fm][fn][r] + bv;
                if (RELU) v = fmaxf(v, 0.f);
                if (EPI == 0) {
                    ((unsigned short*)outp)[(long)(row % N_NODES) * 1024 + (long)(row / N_NODES) * 64 + colg] = f2b(v);
                } else {
                    ((unsigned short*)outp)[(long)row * NTOT + colg] = f2b(v);
                }
            }
        }
    }
}

// -------------- RNN recurrence: 32 seqs/block (625 blocks), 8 steps, w_hh in LDS ----------------
// 40 KiB LDS -> ~4 blocks/CU; xih prefetch ping-pong (t unrolled -> static indexing)
__global__ __launch_bounds__(256) void rnn_kernel(const unsigned short* __restrict__ xih,
                                                  const float* __restrict__ whh,
                                                  unsigned short* __restrict__ rout) {
    __shared__ __align__(16) unsigned short hs[32 * 128];    // 8 KB
    __shared__ __align__(16) unsigned short ws[128 * 128];   // 32 KB
    const int tid = threadIdx.x, lane = tid & 63, wid = tid >> 6;  // 4 waves: col split of 32
    const long i0 = (long)blockIdx.x * 32;

    // stage w_hh -> bf16, XOR-swizzled rows (byte ^= (row&7)<<4)
    #pragma unroll
    for (int p = 0; p < 16; ++p) {
        int idx = p * 256 + tid;
        int n = idx >> 5, k4 = (idx & 31) * 4;
        float4 v = *(const float4*)(whh + n * 128 + k4);
        ushort4 h; h.x = f2b(v.x); h.y = f2b(v.y); h.z = f2b(v.z); h.w = f2b(v.w);
        int byte = (n * 256 + k4 * 2) ^ ((n & 7) << 4);
        *(ushort4*)((char*)ws + byte) = h;
    }
    int4 z = make_int4(0, 0, 0, 0);
    #pragma unroll
    for (int p = 0; p < 2; ++p) ((int4*)hs)[p * 256 + tid] = z;   // 8192 B
    __syncthreads();

    unsigned short x2[2][2][2][4];
    // preload t=0
    #pragma unroll
    for (int fm = 0; fm < 2; ++fm)
        #pragma unroll
        for (int fn = 0; fn < 2; ++fn) {
            int col = wid * 32 + fn * 16 + (lane & 15);
            const unsigned short* src = xih + ((i0 + fm * 16 + (lane >> 4) * 4) * 8 + 0) * 128 + col;
            #pragma unroll
            for (int r = 0; r < 4; ++r) x2[0][fm][fn][r] = src[(long)r * 1024];
        }

    f32x4 acc[2][2];
    #pragma unroll
    for (int t = 0; t < 8; ++t) {
        const int cb = t & 1;
        #pragma unroll
        for (int fm = 0; fm < 2; ++fm)
            #pragma unroll
            for (int fn = 0; fn < 2; ++fn)
                #pragma unroll
                for (int r = 0; r < 4; ++r)
                    acc[fm][fn][r] = b2f(x2[cb][fm][fn][r]);
        // prefetch t+1 (overlaps with MFMAs below)
        if (t < 7) {
            #pragma unroll
            for (int fm = 0; fm < 2; ++fm)
                #pragma unroll
                for (int fn = 0; fn < 2; ++fn) {
                    int col = wid * 32 + fn * 16 + (lane & 15);
                    const unsigned short* src = xih + ((i0 + fm * 16 + (lane >> 4) * 4) * 8 + (t + 1)) * 128 + col;
                    #pragma unroll
                    for (int r = 0; r < 4; ++r) x2[cb ^ 1][fm][fn][r] = src[(long)r * 1024];
                }
        }
        #pragma unroll
        for (int ks = 0; ks < 4; ++ks) {
            bf16x8 a[2], b[2];
            #pragma unroll
            for (int fm = 0; fm < 2; ++fm) {
                int row = fm * 16 + (lane & 15);
                int byte = (row * 256 + ks * 64 + (lane >> 4) * 16) ^ ((row & 7) << 4);
                a[fm] = *(const bf16x8*)((const char*)hs + byte);
            }
            #pragma unroll
            for (int fn = 0; fn < 2; ++fn) {
                int rowb = wid * 32 + fn * 16 + (lane & 15);
                int byte = (rowb * 256 + ks * 64 + (lane >> 4) * 16) ^ ((rowb & 7) << 4);
                b[fn] = *(const bf16x8*)((const char*)ws + byte);
            }
            #pragma unroll
            for (int fm = 0; fm < 2; ++fm)
                #pragma unroll
                for (int fn = 0; fn < 2; ++fn)
                    acc[fm][fn] = __builtin_amdgcn_mfma_f32_16x16x32_bf16(a[fm], b[fn], acc[fm][fn], 0, 0, 0);
        }
        __syncthreads();   // all reads of h_{t-1} done
        #pragma unroll
        for (int fm = 0; fm < 2; ++fm)
            #pragma unroll
            for (int fn = 0; fn < 2; ++fn) {
                int col = wid * 32 + fn * 16 + (lane & 15);
                #pragma unroll
                for (int r = 0; r < 4; ++r) {
                    int row = fm * 16 + (lane >> 4) * 4 + r;
                    float v = tanh_fast(acc[fm][fn][r]);
                    unsigned short hb = f2b(v);
                    int byte = (row * 256 + col * 2) ^ ((row & 7) << 4);
                    *(unsigned short*)((char*)hs + byte) = hb;
                    rout[((i0 + row) * 8 + t) * 128 + col] = hb;
                }
            }
        __syncthreads();   // h_t fully written
    }
}

// -------------- fused 3-layer MLP: 64 rows/block, 8 waves, 48 KiB LDS (target 2 blocks/CU) ----------------
// Column-half pipeline: for h in {0,1}: {p1: y1[:,h*256:+256] -> ys; bar; p2: acc2 += y1h @ w2h^T; bar}
// then for h in {0,1}: {owning waves write y2 half -> ys; bar; p3: a3 += y2h @ w3h^T; bar}; pair-reduce.
// ys row stride 512 B, swizzle (row&15)<<4 bijective within stride.
__global__ __launch_bounds__(512, 4) void mlp_kernel(
        const unsigned short* __restrict__ A,
        const unsigned short* __restrict__ w1f, const float* __restrict__ b1,
        const unsigned short* __restrict__ w2f, const float* __restrict__ b2,
        const unsigned short* __restrict__ w3f, const float* __restrict__ b3,
        float* __restrict__ out) {
    __shared__ __align__(16) char smem[49152];   // As 16K | ys 32K
    char* As = smem;
    char* ys = smem + 16384;

    const int tid = threadIdx.x, lane = tid & 63, w = tid >> 6;
    const long r0 = (long)blockIdx.x * 64;

    // stage A tile 64x128 bf16, swizzled
    #pragma unroll
    for (int p = 0; p < 2; ++p) {
        int idx = p * 512 + tid;              // 1024 int4
        int row = idx >> 4, c16 = idx & 15;
        int4 v = *(const int4*)(A + (r0 + row) * 128 + c16 * 8);
        int byte = (row * 256 + c16 * 16) ^ ((row & 15) << 4);
        *(int4*)(As + byte) = v;
    }
    __syncthreads();

    f32x4 acc2[4][4];   // y2 accumulator, persists across both halves
    #pragma unroll
    for (int fm = 0; fm < 4; ++fm)
        #pragma unroll
        for (int fn = 0; fn < 4; ++fn) acc2[fm][fn] = (f32x4){0.f, 0.f, 0.f, 0.f};

    // ---- phases 1+2 in column-halves ----
    #pragma unroll
    for (int half = 0; half < 2; ++half) {
        // p1: y1 half cols [half*256 + w*32, +32), fn-outer to cap registers
        #pragma unroll
        for (int fn = 0; fn < 2; ++fn) {
            f32x4 accy[4];
            #pragma unroll
            for (int fm = 0; fm < 4; ++fm) accy[fm] = (f32x4){0.f, 0.f, 0.f, 0.f};
            #pragma unroll
            for (int ks = 0; ks < 4; ++ks) {
                bf16x8 b = *(const bf16x8*)(w1f + (long)((half * 16 + w * 2 + fn) * 4 + ks) * 512 + lane * 8);
                #pragma unroll
                for (int fm = 0; fm < 4; ++fm) {
                    int row = fm * 16 + (lane & 15);
                    bf16x8 a = *(const bf16x8*)(As + ((row * 256 + ks * 64 + (lane >> 4) * 16) ^ ((row & 15) << 4)));
                    accy[fm] = __builtin_amdgcn_mfma_f32_16x16x32_bf16(a, b, accy[fm], 0, 0, 0);
                }
            }
            int lcol = w * 32 + fn * 16 + (lane & 15);
            float bv = b1[half * 256 + lcol];
            #pragma unroll
            for (int fm = 0; fm < 4; ++fm)
                #pragma unroll
                for (int r = 0; r < 4; ++r) {
                    int row = fm * 16 + (lane >> 4) * 4 + r;
                    float v = fmaxf(accy[fm][r] + bv, 0.f);
                    int byte = (row * 512 + lcol * 2) ^ ((row & 15) << 4);
                    *(unsigned short*)(ys + byte) = f2b(v);
                }
        }
        __syncthreads();   // y1 half visible
        // p2 partial: acc2 += y1h @ w2h^T (k = half*256 .. +256)
        #pragma unroll
        for (int ks = 0; ks < 8; ++ks) {
            bf16x8 a[4], b[4];
            #pragma unroll
            for (int fm = 0; fm < 4; ++fm) {
                int row = fm * 16 + (lane & 15);
                a[fm] = *(const bf16x8*)(ys + ((row * 512 + ks * 64 + (lane >> 4) * 16) ^ ((row & 15) << 4)));
            }
            #pragma unroll
            for (int fn = 0; fn < 4; ++fn)
                b[fn] = *(const bf16x8*)(w2f + (long)((w * 4 + fn) * 16 + half * 8 + ks) * 512 + lane * 8);
            #pragma unroll
            for (int fm = 0; fm < 4; ++fm)
                #pragma unroll
                for (int fn = 0; fn < 4; ++fn)
                    acc2[fm][fn] = __builtin_amdgcn_mfma_f32_16x16x32_bf16(a[fm], b[fn], acc2[fm][fn], 0, 0, 0);
        }
        __syncthreads();   // y1h reads done -> ys reusable
    }

    // ---- phase 3 in column-halves of y2 ----
    const int fn3 = w & 3, q = w >> 2;
    f32x4 a3[4];
    #pragma unroll
    for (int fm = 0; fm < 4; ++fm) a3[fm] = (f32x4){0.f, 0.f, 0.f, 0.f};
    #pragma unroll
    for (int half = 0; half < 2; ++half) {
        if (q == half) {   // waves owning y2 cols [half*256, +256) write their slice (+b2, relu)
            #pragma unroll
            for (int fn = 0; fn < 4; ++fn) {
                int lcol = (w & 3) * 64 + fn * 16 + (lane & 15);
                float bv = b2[w * 64 + fn * 16 + (lane & 15)];
                #pragma unroll
                for (int fm = 0; fm < 4; ++fm)
                    #pragma unroll
                    for (int r = 0; r < 4; ++r) {
                        int row = fm * 16 + (lane >> 4) * 4 + r;
                        float v = fmaxf(acc2[fm][fn][r] + bv, 0.f);
                        int byte = (row * 512 + lcol * 2) ^ ((row & 15) << 4);
                        *(unsigned short*)(ys + byte) = f2b(v);
                    }
            }
        }
        __syncthreads();   // y2 half visible
        #pragma unroll
        for (int ksl = 0; ksl < 4; ++ksl) {
            int kloc = q * 4 + ksl;
            bf16x8 b = *(const bf16x8*)(w3f + (long)(fn3 * 16 + half * 8 + kloc) * 512 + lane * 8);
            #pragma unroll
            for (int fm = 0; fm < 4; ++fm) {
                int row = fm * 16 + (lane & 15);
                bf16x8 a = *(const bf16x8*)(ys + ((row * 512 + kloc * 64 + (lane >> 4) * 16) ^ ((row & 15) << 4)));
                a3[fm] = __builtin_amdgcn_mfma_f32_16x16x32_bf16(a, b, a3[fm], 0, 0, 0);
            }
        }
        __syncthreads();   // y2h reads done
    }

    // pair-reduce (q=1 dumps, q=0 adds + stores); ys reused as f32 scratch (4 x 1104 f32 = 17.6 KB)
    if (w >= 4) {
        float* rb = (float*)(ys) + (w - 4) * 1104;
        #pragma unroll
        for (int fm = 0; fm < 4; ++fm)
            #pragma unroll
            for (int r = 0; r < 4; ++r)
                rb[(fm * 16 + (lane >> 4) * 4 + r) * 17 + (lane & 15)] = a3[fm][r];
    }
    __syncthreads();
    if (w < 4) {
        float* rb = (float*)(ys) + w * 1104;
        float bv = b3[fn3 * 16 + (lane & 15)];
        #pragma unroll
        for (int fm = 0; fm < 4; ++fm)
            #pragma unroll
            for (int r = 0; r < 4; ++r) {
                int row = fm * 16 + (lane >> 4) * 4 + r;
                float v = a3[fm][r] + rb[row * 17 + (lane & 15)] + bv;
                long vr = r0 + row;   // flat M row = v*8 + t
                out[((vr >> 3) * 10 + (vr & 7)) * 64 + fn3 * 16 + (lane & 15)] = v;
            }
    }
}

extern "C" void kernel_launch(void* const* d_in, const int* in_sizes, int n_in,
                              void* d_out, int out_size, void* d_ws, size_t ws_size,
                              hipStream_t stream) {
    const float* x     = (const float*)d_in[0];
    const int*   ei    = (const int*)  d_in[1];
    const float* ew    = (const float*)d_in[2];
    const float* gcn_w = (const float*)d_in[3];
    const float* gcn_b = (const float*)d_in[4];
    const float* w_ih  = (const float*)d_in[5];
    const float* w_hh  = (const float*)d_in[6];
    const float* b_ih  = (const float*)d_in[7];
    const float* b_hh  = (const float*)d_in[8];
    const float* w1    = (const float*)d_in[9];
    const float* b1    = (const float*)d_in[10];
    const float* w2    = (const float*)d_in[11];
    const float* b2    = (const float*)d_in[12];
    const float* w3    = (const float*)d_in[13];
    const float* b3    = (const float*)d_in[14];

    // ---- workspace layout (peak ~107 MiB) ----
    char* ws = (char*)d_ws;
    unsigned short* xlt  = (unsigned short*)ws;                  // [N][16][64] bf16, dead after aggregate
    unsigned short* rnno = (unsigned short*)ws;                  // [160000][128] bf16
    unsigned short* gc   = (unsigned short*)(ws + 41943040L);    // [160000][64] bf16
    unsigned short* xih  = (unsigned short*)(ws + 62914560L);    // [160000][128] bf16
    unsigned short* w1f  = (unsigned short*)(ws + 104857600L);   // 128 KB
    unsigned short* w2f  = (unsigned short*)(ws + 104988672L);   // 512 KB
    unsigned short* w3f  = (unsigned short*)(ws + 105512960L);   // 64 KB
    char* sm = ws + 106954752L;
    float* deg    = (float*)(sm);
    float* dinv   = (float*)(sm + (64 << 10));
    int*   cnt    = (int*)  (sm + (128 << 10));
    int*   offs   = (int*)  (sm + (192 << 10));
    int*   cursor = (int*)  (sm + (256 << 10));
    int*   erow   = (int*)  (sm + (320 << 10));
    float* enorm  = (float*)(sm + (1 << 20));

    hipMemsetAsync(d_out, 0, (size_t)out_size * sizeof(float), stream);  // prediction slots stay 0

    init_kernel<<<40, 256, 0, stream>>>(deg, cnt);
    deg_add_kernel<<<625, 256, 0, stream>>>(ei, ew, deg, cnt);
    dinv_kernel<<<40, 256, 0, stream>>>(deg, dinv);
    scan_kernel<<<1, 1024, 0, stream>>>(cnt, offs, cursor);
    fill_kernel<<<625, 256, 0, stream>>>(ei, ew, dinv, cursor, erow, enorm);

    wconv_kernel<4, 128><<<32, 256, 0, stream>>>(w1, w1f);     // NF=32
    wconv_kernel<16, 512><<<128, 256, 0, stream>>>(w2, w2f);   // NF=32
    wconv_kernel<16, 512><<<16, 256, 0, stream>>>(w3, w3f);    // NF=4

    // xl^T[n][g][f] = x[g,n,:] . gcn_w[f,:]  (bf16 out, scattered)
    gemm_kernel<64, 64, 64, true, 0, false><<<dim3(1250, 1), 256, 0, stream>>>(x, gcn_w, nullptr, nullptr, xlt);
    aggregate_kernel<<<5000, 256, 0, stream>>>(xlt, erow, enorm, offs, dinv, gcn_b, gc);
    // xih[v][h] = gc[v,:] . w_ih[h,:] + b_ih + b_hh  (bf16 out)
    gemm_kernel<128, 128, 64, false, 2, false><<<dim3(1250, 1), 256, 0, stream>>>(gc, w_ih, b_ih, b_hh, xih);
    rnn_kernel<<<625, 256, 0, stream>>>(xih, w_hh, rnno);
    mlp_kernel<<<2500, 512, 0, stream>>>(rnno, w1f, b1, w2f, b2, w3f, b3, (float*)d_out);
}